// Round 17
// baseline (407.747 us; speedup 1.0000x reference)
//
#include <hip/hip_runtime.h>
#include <hip/hip_fp16.h>
#include <math.h>

#define NFEAT 128
#define NHID  64
#define ATH996 3.106303f   // artanh(0.996)
#define CHUNK 4096         // edges per sort block
#define CAP   6144         // fixed capacity per 256-node bucket (mean ~4092)

typedef __attribute__((ext_vector_type(8))) _Float16 half8;
typedef __attribute__((ext_vector_type(4))) float floatx4;
typedef unsigned short ushort_t;
typedef unsigned long long u64;

__device__ __forceinline__ float wave_sum(float v) {
#pragma unroll
    for (int m = 1; m < 64; m <<= 1) v += __shfl_xor(v, m, 64);
    return v;
}

__device__ __forceinline__ float fast_tanh(float x) {
    float e = __expf(2.f * x);
    return 1.f - 2.f / (e + 1.f);
}

__device__ __forceinline__ float artanh_clip(float v) {
    const float lim = 0.99999988f;  // float(1 - 1e-7)
    v = fminf(fmaxf(v, -lim), lim);
    return 0.5f * __logf((1.f + v) / (1.f - v));
}

__device__ __forceinline__ ushort_t f2h(float f) {
    __half h = __float2half(f);
    return *(ushort_t*)&h;
}

__device__ __forceinline__ unsigned pk2h(float a, float b) {
    return (unsigned)f2h(a) | ((unsigned)f2h(b) << 16);
}

// packed edge: bits[31:15] = src (17b), bits[14:0] = fp16(adj) sans sign
__device__ __forceinline__ __half pe_adjh(unsigned p) {
    return __ushort_as_half((ushort_t)(p & 0x7fffu));
}

// ---- one-shot prep: weight packs (fp16) + biases + cursor zeroing -----------
__global__ __launch_bounds__(256) void k_prep(
        const float* __restrict__ W1, const float* __restrict__ W2,
        const float* __restrict__ W3, const float* __restrict__ W4,
        const float* __restrict__ W5, const float* __restrict__ b1,
        const float* __restrict__ b2, const float* __restrict__ b3,
        ushort_t* __restrict__ Bpk1, ushort_t* __restrict__ Bpk2,
        ushort_t* __restrict__ Bpk3, ushort_t* __restrict__ Bpk4,
        ushort_t* __restrict__ Bpk5, float* __restrict__ hbs,
        float* __restrict__ hbns, int* __restrict__ gCur, int nb) {
    int bid = blockIdx.x, tid = threadIdx.x;
    if (bid >= 75) {
        for (int t = tid; t < nb; t += 256) gCur[t] = 0;
        return;
    }
    if (bid < 64) {
        const float* W; ushort_t* Bpk; int K, o;
        if (bid < 32)      { W = W1; Bpk = Bpk1; K = 128; o = bid * 256 + tid; }
        else if (bid < 48) { W = W2; Bpk = Bpk2; K = 64;  o = (bid - 32) * 256 + tid; }
        else               { W = W3; Bpk = Bpk3; K = 64;  o = (bid - 48) * 256 + tid; }
        int j = o & 7, c = (o >> 3) & 15, nf = (o >> 7) & 3, hi = (o >> 9) & 3,
            ks = o >> 11;
        Bpk[o] = f2h(W[(nf * 16 + c) * K + ks * 32 + hi * 8 + j]);
    } else if (bid < 72) {
        int o = (bid - 64) * 256 + tid;
        int j = o & 7, c = (o >> 3) & 15, nf = (o >> 7) & 1, hi = (o >> 8) & 3,
            ks = o >> 10;
        Bpk4[o] = f2h(W4[(nf * 16 + c) * 64 + ks * 32 + hi * 8 + j]);
    } else if (bid < 74) {
        int o = (bid - 72) * 256 + tid;
        if (o < 512) {
            int j = o & 7, c = (o >> 3) & 15, hi = o >> 7;
            Bpk5[o] = f2h(W5[c * 32 + hi * 8 + j]);
        }
    } else {
        if (tid < 192) {
            int wv = tid >> 6, lane = tid & 63;
            const float* b = (wv == 0) ? b1 : (wv == 1) ? b2 : b3;
            float bv = b[lane];
            float bn = fmaxf(sqrtf(wave_sum(bv * bv)), 1e-15f);
            float th = fast_tanh(bn);
            float f = th / bn;
            float hn = th;
            if (th > 0.996f) { f = 0.996f / bn; hn = 0.996f; }
            hbs[wv * 64 + lane] = bv * f;
            if (lane == 0) hbns[wv] = hn;
        }
    }
}

// epilogue transform on one row's 4 nf-values (16-lane-group reductions)
__device__ __forceinline__ void epi_vals(const float vin[4], float pn,
        float hbn, const float* __restrict__ hb, int c, float outv[4]) {
    float pp = 0.f;
#pragma unroll
    for (int nf = 0; nf < 4; ++nf) pp += vin[nf] * vin[nf];
#pragma unroll
    for (int m = 1; m < 16; m <<= 1) pp += __shfl_xor(pp, m, 64);
    float mpn = sqrtf(pp);
    float an = artanh_clip(pn);
    if (hbn <= 1e-15f) {
        float targ = (mpn / pn) * an;
        float scale = (targ > ATH996) ? (ATH996 / mpn) : (an / pn);
        if (mpn <= 1e-15f) scale = 0.f;
#pragma unroll
        for (int nf = 0; nf < 4; ++nf) outv[nf] = vin[nf] * scale;
    } else {
        float targ = (mpn / pn) * an;
        float th = fast_tanh(targ);
        float rn = fminf(th, 0.996f);
        float rs = (mpn <= 1e-15f) ? 0.f : (rn / mpn);
        float res[4], xyp = 0.f;
#pragma unroll
        for (int nf = 0; nf < 4; ++nf) {
            res[nf] = vin[nf] * rs;
            xyp += res[nf] * hb[nf * 16 + c];
        }
#pragma unroll
        for (int m = 1; m < 16; m <<= 1) xyp += __shfl_xor(xyp, m, 64);
        float x2 = rn * rn, y2 = hbn * hbn;
        float den = fmaxf(1.f + 2.f * xyp + x2 * y2, 1e-15f);
        float ca = (1.f + 2.f * xyp + y2) / den, cb = (1.f - x2) / den;
        float mv[4], mm = 0.f;
#pragma unroll
        for (int nf = 0; nf < 4; ++nf) {
            mv[nf] = ca * res[nf] + cb * hb[nf * 16 + c];
            mm += mv[nf] * mv[nf];
        }
#pragma unroll
        for (int m = 1; m < 16; m <<= 1) mm += __shfl_xor(mm, m, 64);
        float mn = sqrtf(mm);
        float mc = fminf(fmaxf(mn, 1e-15f), 0.996f);
        float msc = ((mn > 0.996f) ? (0.996f / mn) : 1.f) * artanh_clip(mc) / mc;
#pragma unroll
        for (int nf = 0; nf < 4; ++nf) outv[nf] = mv[nf] * msc;
    }
}

// fused: blocks [0,sortBlocks) = edge bucket-scatter (fixed-capacity regions);
// blocks [sortBlocks, ...) = layer-1 GEMM. Independent -> true overlap.
__global__ __launch_bounds__(256) void k_gemm1_scatter(
        const float* __restrict__ x, const ushort_t* __restrict__ Bpk,
        const float* __restrict__ hb, const float* __restrict__ hbn_p,
        ushort_t* __restrict__ htout, int n, int sortBlocks,
        const int* __restrict__ dst, const int* __restrict__ src,
        const float* __restrict__ adj, int* __restrict__ gCur,
        u64* __restrict__ gStage, int e, int nb) {
    __shared__ __align__(16) unsigned char smem[41984];
    int tid = threadIdx.x;
    if ((int)blockIdx.x < sortBlocks) {
        u64* stage   = (u64*)smem;                     // CHUNK*8 = 32768
        int* cnt     = (int*)(smem + 32768);           // 512*4
        int* excl    = cnt + 512;
        int* rcnt    = excl + 512;
        int* myBase  = rcnt + 512;
        int* s       = myBase + 512;                   // 256*4
        int start = blockIdx.x * CHUNK, end = min(e, start + CHUNK);
        for (int t = tid; t < nb; t += 256) { cnt[t] = 0; rcnt[t] = 0; }
        __syncthreads();
        for (int i = start + tid; i < end; i += 256)
            atomicAdd(&cnt[dst[i] >> 8], 1);
        __syncthreads();
        int v0 = (2 * tid < nb) ? cnt[2 * tid] : 0;
        int v1 = (2 * tid + 1 < nb) ? cnt[2 * tid + 1] : 0;
        int tsum = v0 + v1;
        s[tid] = tsum; __syncthreads();
        for (int o = 1; o < 256; o <<= 1) {
            int v = (tid >= o) ? s[tid - o] : 0;
            __syncthreads();
            s[tid] += v;
            __syncthreads();
        }
        int ex = s[tid] - tsum;
        if (2 * tid < nb) excl[2 * tid] = ex;
        if (2 * tid + 1 < nb) excl[2 * tid + 1] = ex + v0;
        __syncthreads();
        for (int t = tid; t < nb; t += 256)
            if (cnt[t]) myBase[t] = t * CAP + atomicAdd(&gCur[t], cnt[t]);
        for (int i = start + tid; i < end; i += 256) {
            int d = dst[i];
            int b = d >> 8;
            unsigned ab = (unsigned)__half_as_ushort(__float2half(adj[i])) & 0x7fffu;
            u64 u = ((u64)(unsigned)d << 32) |
                    (u64)(((unsigned)src[i] << 15) | ab);
            int r = atomicAdd(&rcnt[b], 1);
            stage[excl[b] + r] = u;
        }
        __syncthreads();
        int sz = end - start;
        for (int j = tid; j < sz; j += 256) {
            u64 u = stage[j];
            int b = (int)(u >> 40) & 0x1ff;   // dst>>8
            gStage[myBase[b] + (j - excl[b])] = u;
        }
        return;
    }
    // ---- layer-1 GEMM (scale folded into epilogue), fp16 ----
    constexpr int RB = 256;
    unsigned char* As = smem;                           // 64*256 = 16384
    float* pns = (float*)(smem + 16384);                // 64
    float* fs  = pns + 64;                              // 64
    int wv = tid >> 6, lane = tid & 63;
    int grp = lane >> 4, l = lane & 15;
    int rowBase = ((int)blockIdx.x - sortBlocks) * 64;
#pragma unroll
    for (int it = 0; it < 4; ++it) {
        int row = wv * 16 + it * 4 + grp, rg = rowBase + row;
        float4 va = make_float4(0.f, 0.f, 0.f, 0.f), vb = va;
        if (rg < n) {
            const float4* xr = (const float4*)(x + (size_t)rg * NFEAT + l * 8);
            va = xr[0]; vb = xr[1];
        }
        uint4 pk;
        pk.x = pk2h(va.x, va.y); pk.y = pk2h(va.z, va.w);
        pk.z = pk2h(vb.x, vb.y); pk.w = pk2h(vb.z, vb.w);
        unsigned byte = (unsigned)(row * RB + l * 16) ^ ((row & 7) << 4);
        *(uint4*)(As + byte) = pk;
        float ss = va.x * va.x + va.y * va.y + va.z * va.z + va.w * va.w +
                   vb.x * vb.x + vb.y * vb.y + vb.z * vb.z + vb.w * vb.w;
#pragma unroll
        for (int m = 1; m < 16; m <<= 1) ss += __shfl_xor(ss, m, 64);
        if (l == 0) {
            float nr = fmaxf(sqrtf(ss), 1e-15f);
            float th = fast_tanh(nr);
            float f = th / nr;
            float pn = fmaxf(th, 1e-15f);
            if (th > 0.996f) { f = 0.996f / nr; pn = 0.996f; }
            pns[row] = pn; fs[row] = f;
        }
    }
    int hi = lane >> 4, c = lane & 15;
    half8 bf[4][4];
#pragma unroll
    for (int ks = 0; ks < 4; ++ks)
#pragma unroll
        for (int nf = 0; nf < 4; ++nf)
            bf[ks][nf] = *(const half8*)(Bpk + (((size_t)(ks * 4 + hi) * 4 + nf) * 16 + c) * 8);
    floatx4 acc[4];
#pragma unroll
    for (int nf = 0; nf < 4; ++nf)
#pragma unroll
        for (int r = 0; r < 4; ++r) acc[nf][r] = 0.f;
    int arow = wv * 16 + c;
#pragma unroll
    for (int ks = 0; ks < 4; ++ks) {
        unsigned byte = (unsigned)(arow * RB + ks * 64 + hi * 16) ^ ((arow & 7) << 4);
        half8 af = *(const half8*)(As + byte);
#pragma unroll
        for (int nf = 0; nf < 4; ++nf)
            acc[nf] = __builtin_amdgcn_mfma_f32_16x16x32_f16(af, bf[ks][nf], acc[nf], 0, 0, 0);
    }
    float hbn = hbn_p[0];
#pragma unroll
    for (int r = 0; r < 4; ++r) {
        int row = wv * 16 + hi * 4 + r, rg = rowBase + row;
        float f = fs[row];
        float vin[4], outv[4];
#pragma unroll
        for (int nf = 0; nf < 4; ++nf) vin[nf] = acc[nf][r] * f;
        epi_vals(vin, pns[row], hbn, hb, c, outv);
        if (rg < n) {
#pragma unroll
            for (int nf = 0; nf < 4; ++nf)
                htout[(size_t)rg * 64 + nf * 16 + c] = f2h(outv[nf]);
        }
    }
}

// per-bucket finalize: local node histogram -> (beg,end) pairs; rank-scatter pe
__global__ __launch_bounds__(256) void k_bfinal(const u64* __restrict__ gStage,
        const int* __restrict__ gCur, int* __restrict__ off2,
        unsigned* __restrict__ pe, int n) {
    __shared__ int ncnt[256], nexcl[256], rcnt[256], s[256];
    int tid = threadIdx.x, b = blockIdx.x;
    int base = b * CAP;
    int ecnt = gCur[b];
    int nbeg = b << 8;
    ncnt[tid] = 0; rcnt[tid] = 0;
    __syncthreads();
    for (int j = tid; j < ecnt; j += 256) {
        int dl = ((int)(gStage[base + j] >> 32) & 0x1ffff) - nbeg;
        atomicAdd(&ncnt[dl], 1);
    }
    __syncthreads();
    int v = ncnt[tid];
    s[tid] = v; __syncthreads();
    for (int o = 1; o < 256; o <<= 1) {
        int t2 = (tid >= o) ? s[tid - o] : 0;
        __syncthreads();
        s[tid] += t2;
        __syncthreads();
    }
    nexcl[tid] = s[tid] - v;
    int node = nbeg + tid;
    if (node < n) {
        off2[2 * node]     = base + nexcl[tid];
        off2[2 * node + 1] = base + nexcl[tid] + v;
    }
    __syncthreads();
    for (int j = tid; j < ecnt; j += 256) {
        u64 u = gStage[base + j];
        int dl = ((int)(u >> 32) & 0x1ffff) - nbeg;
        int r = atomicAdd(&rcnt[dl], 1);
        pe[base + nexcl[dl] + r] = (unsigned)u;
    }
}

// layers 2/3 GEMM (8B/lane staging), fp16
__global__ __launch_bounds__(256) void k_gemm64(
        const ushort_t* __restrict__ h, const float* __restrict__ nrm_in,
        const ushort_t* __restrict__ Bpk, const float* __restrict__ hb,
        const float* __restrict__ hbn_p, ushort_t* __restrict__ htout, int n) {
    constexpr int RB = 128;
    __shared__ __align__(16) unsigned char As[64 * RB];
    int tid = threadIdx.x, wv = tid >> 6, lane = tid & 63;
    int grp = lane >> 4, l = lane & 15;
    int rowBase = blockIdx.x * 64;
#pragma unroll
    for (int it = 0; it < 4; ++it) {
        int row = wv * 16 + it * 4 + grp, rg = rowBase + row;
        uint2 pk = make_uint2(0u, 0u);
        if (rg < n) pk = *(const uint2*)(h + (size_t)rg * 64 + l * 4);
        unsigned byte = (unsigned)(row * RB + l * 8) ^ ((row & 7) << 4);
        *(uint2*)(As + byte) = pk;
    }
    int hi = lane >> 4, c = lane & 15;
    half8 bf[2][4];
#pragma unroll
    for (int ks = 0; ks < 2; ++ks)
#pragma unroll
        for (int nf = 0; nf < 4; ++nf)
            bf[ks][nf] = *(const half8*)(Bpk + (((size_t)(ks * 4 + hi) * 4 + nf) * 16 + c) * 8);
    floatx4 acc[4];
#pragma unroll
    for (int nf = 0; nf < 4; ++nf)
#pragma unroll
        for (int r = 0; r < 4; ++r) acc[nf][r] = 0.f;
    int arow = wv * 16 + c;
#pragma unroll
    for (int ks = 0; ks < 2; ++ks) {
        unsigned byte = (unsigned)(arow * RB + ks * 64 + hi * 16) ^ ((arow & 7) << 4);
        half8 af = *(const half8*)(As + byte);
#pragma unroll
        for (int nf = 0; nf < 4; ++nf)
            acc[nf] = __builtin_amdgcn_mfma_f32_16x16x32_f16(af, bf[ks][nf], acc[nf], 0, 0, 0);
    }
    float hbn = hbn_p[0];
#pragma unroll
    for (int r = 0; r < 4; ++r) {
        int row = wv * 16 + hi * 4 + r, rg = rowBase + row;
        float pn = (rg < n) ? nrm_in[rg] : 1e-15f;
        float vin[4], outv[4];
#pragma unroll
        for (int nf = 0; nf < 4; ++nf) vin[nf] = acc[nf][r];
        epi_vals(vin, pn, hbn, hb, c, outv);
        if (rg < n) {
#pragma unroll
            for (int nf = 0; nf < 4; ++nf)
                htout[(size_t)rg * 64 + nf * 16 + c] = f2h(outv[nf]);
        }
    }
}

// feature-quartered aggregation: blockIdx&7 -> (assumed) XCD; quarter = x>>1.
// Each XCD touches only its 3.2MB quarter of ht -> L2-resident gathers.
// Writes raw weighted sums (no activation) to agg[N,64] fp16.
__global__ __launch_bounds__(256) void k_aggq(
        const ushort_t* __restrict__ ht, const int* __restrict__ off2,
        const unsigned* __restrict__ pe, ushort_t* __restrict__ aggout, int n) {
    int xq = (int)blockIdx.x & 7;
    int q = xq >> 1;
    int tile = ((int)blockIdx.x >> 3) * 2 + (xq & 1);
    int tid = threadIdx.x;
    int l4 = tid & 3;
    int node = tile * 64 + (tid >> 2);
    if (node >= n) return;
    int2 be = *(const int2*)(off2 + 2 * node);
    int beg = be.x, end = be.y;
    const char* hb8 = (const char*)ht + q * 32 + l4 * 8;
    __half2 ax[4], ay[4];
#pragma unroll
    for (int u = 0; u < 4; ++u) {
        ax[u] = __float2half2_rn(0.f);
        ay[u] = __float2half2_rn(0.f);
    }
    int e = beg;
    for (; e + 7 < end; e += 8) {
        unsigned p[8];
#pragma unroll
        for (int u = 0; u < 8; ++u) p[u] = pe[e + u];
        uint2 rr[8];
#pragma unroll
        for (int u = 0; u < 8; ++u)
            rr[u] = *(const uint2*)(hb8 + ((size_t)(p[u] >> 15) << 7));
#pragma unroll
        for (int u = 0; u < 8; ++u) {
            __half2 w2 = __half2half2(pe_adjh(p[u]));
            ax[u & 3] = __hfma2(w2, *(__half2*)&rr[u].x, ax[u & 3]);
            ay[u & 3] = __hfma2(w2, *(__half2*)&rr[u].y, ay[u & 3]);
        }
    }
    for (; e < end; ++e) {
        unsigned p = pe[e];
        uint2 r = *(const uint2*)(hb8 + ((size_t)(p >> 15) << 7));
        __half2 w2 = __half2half2(pe_adjh(p));
        ax[0] = __hfma2(w2, *(__half2*)&r.x, ax[0]);
        ay[0] = __hfma2(w2, *(__half2*)&r.y, ay[0]);
    }
    float f0 = 0.f, f1 = 0.f, f2 = 0.f, f3 = 0.f;
#pragma unroll
    for (int u = 0; u < 4; ++u) {
        float2 vx = __half22float2(ax[u]);
        float2 vy = __half22float2(ay[u]);
        f0 += vx.x; f1 += vx.y; f2 += vy.x; f3 += vy.y;
    }
    uint2 ov = make_uint2(pk2h(f0, f1), pk2h(f2, f3));
    *(uint2*)((char*)aggout + (size_t)node * 128 + q * 32 + l4 * 8) = ov;
}

// streaming HypAct over agg rows: norm + tanh/artanh tail, 16 lanes/node
template <bool TANGENT_OUT>
__global__ __launch_bounds__(256) void k_act(
        const ushort_t* __restrict__ agg, ushort_t* __restrict__ hout,
        float* __restrict__ nrm_out, int n) {
    int tid = threadIdx.x;
    int grp = tid >> 4, l = tid & 15;
    int node = blockIdx.x * 16 + grp;
    if (node >= n) return;
    uint2 v = *(const uint2*)((const char*)agg + (size_t)node * 128 + l * 8);
    float2 vx = __half22float2(*(__half2*)&v.x);
    float2 vy = __half22float2(*(__half2*)&v.y);
    float f0 = vx.x, f1 = vx.y, f2 = vy.x, f3 = vy.y;
    float ss = f0 * f0 + f1 * f1 + f2 * f2 + f3 * f3;
#pragma unroll
    for (int m = 1; m < 16; m <<= 1) ss += __shfl_xor(ss, m, 64);
    float un = fmaxf(sqrtf(ss), 1e-15f);
    float thu = fast_tanh(un);
    float pf = thu / un, pn = thu;
    if (thu > 0.996f) { pf = 0.996f / un; pn = 0.996f; }
    float pnc = fmaxf(pn, 1e-15f);
    float ls = artanh_clip(pnc) / pnc * pf;   // logmap0(proj(expmap0(.))) scale
    float t0 = fmaxf(ls * f0, 0.f), t1 = fmaxf(ls * f1, 0.f);
    float t2 = fmaxf(ls * f2, 0.f), t3 = fmaxf(ls * f3, 0.f);
    float ss2 = t0 * t0 + t1 * t1 + t2 * t2 + t3 * t3;
#pragma unroll
    for (int m = 1; m < 16; m <<= 1) ss2 += __shfl_xor(ss2, m, 64);
    float tn = fmaxf(sqrtf(ss2), 1e-15f);
    uint2 ov;
    if (TANGENT_OUT) {
        float sc = (tn > ATH996) ? (ATH996 / tn) : 1.f;
        ov = make_uint2(pk2h(t0 * sc, t1 * sc), pk2h(t2 * sc, t3 * sc));
    } else {
        float tht = fast_tanh(tn);
        float rf = tht / tn, rn = tht;
        if (tht > 0.996f) { rf = 0.996f / tn; rn = 0.996f; }
        ov = make_uint2(pk2h(rf * t0, rf * t1), pk2h(rf * t2, rf * t3));
        if (l == 0) nrm_out[node] = fmaxf(rn, 1e-15f);
    }
    *(uint2*)((char*)hout + (size_t)node * 128 + l * 8) = ov;
}

// MFMA head: z = relu(t@W4.T+b4); out = log_softmax(z@W5.T+b5), fp16
__global__ __launch_bounds__(256) void k_head(
        const ushort_t* __restrict__ t_in, const ushort_t* __restrict__ Bpk4,
        const float* __restrict__ b4, const ushort_t* __restrict__ Bpk5,
        const float* __restrict__ b5, float* __restrict__ out, int n) {
    constexpr int RB = 128;
    __shared__ __align__(16) unsigned char As[64 * RB];
    __shared__ __align__(16) unsigned char Zs[4][16 * 80];  // 80B rows: 2-way max
    int tid = threadIdx.x, wv = tid >> 6, lane = tid & 63;
    int grp = lane >> 4, l = lane & 15;
    int rowBase = blockIdx.x * 64;
#pragma unroll
    for (int it = 0; it < 4; ++it) {
        int row = wv * 16 + it * 4 + grp, rg = rowBase + row;
        uint2 pk = make_uint2(0u, 0u);
        if (rg < n) pk = *(const uint2*)(t_in + (size_t)rg * 64 + l * 4);
        unsigned byte = (unsigned)(row * RB + l * 8) ^ ((row & 7) << 4);
        *(uint2*)(As + byte) = pk;
    }
    int hi = lane >> 4, c = lane & 15;
    half8 bf4[2][2];
#pragma unroll
    for (int ks = 0; ks < 2; ++ks)
#pragma unroll
        for (int nf = 0; nf < 2; ++nf)
            bf4[ks][nf] = *(const half8*)(Bpk4 + (((size_t)(ks * 4 + hi) * 2 + nf) * 16 + c) * 8);
    floatx4 acc[2];
#pragma unroll
    for (int nf = 0; nf < 2; ++nf)
#pragma unroll
        for (int r = 0; r < 4; ++r) acc[nf][r] = 0.f;
    int arow = wv * 16 + c;
#pragma unroll
    for (int ks = 0; ks < 2; ++ks) {
        unsigned byte = (unsigned)(arow * RB + ks * 64 + hi * 16) ^ ((arow & 7) << 4);
        half8 af = *(const half8*)(As + byte);
#pragma unroll
        for (int nf = 0; nf < 2; ++nf)
            acc[nf] = __builtin_amdgcn_mfma_f32_16x16x32_f16(af, bf4[ks][nf], acc[nf], 0, 0, 0);
    }
    float bb0 = b4[c], bb1 = b4[16 + c];
#pragma unroll
    for (int r = 0; r < 4; ++r) {
        int zr = hi * 4 + r;
        *(ushort_t*)(Zs[wv] + zr * 80 + c * 2) = f2h(fmaxf(acc[0][r] + bb0, 0.f));
        *(ushort_t*)(Zs[wv] + zr * 80 + (16 + c) * 2) = f2h(fmaxf(acc[1][r] + bb1, 0.f));
    }
    half8 bf5 = *(const half8*)(Bpk5 + ((size_t)(hi * 16 + c)) * 8);
    half8 zf = *(const half8*)(Zs[wv] + c * 80 + hi * 16);
    floatx4 acc5;
#pragma unroll
    for (int r = 0; r < 4; ++r) acc5[r] = 0.f;
    acc5 = __builtin_amdgcn_mfma_f32_16x16x32_f16(zf, bf5, acc5, 0, 0, 0);
    float b5v = b5[c];
#pragma unroll
    for (int r = 0; r < 4; ++r) {
        float y = acc5[r] + b5v;
        float mx = y;
#pragma unroll
        for (int mk = 1; mk < 16; mk <<= 1) mx = fmaxf(mx, __shfl_xor(mx, mk, 64));
        float sm = __expf(y - mx);
#pragma unroll
        for (int mk = 1; mk < 16; mk <<= 1) sm += __shfl_xor(sm, mk, 64);
        int rg = rowBase + wv * 16 + hi * 4 + r;
        if (rg < n) out[(size_t)rg * 16 + c] = y - mx - __logf(sm);
    }
}

extern "C" void kernel_launch(void* const* d_in, const int* in_sizes, int n_in,
                              void* d_out, int out_size, void* d_ws, size_t ws_size,
                              hipStream_t stream) {
    const float* x   = (const float*)d_in[0];
    const int*   src = (const int*)d_in[1];
    const int*   dst = (const int*)d_in[2];
    const float* adj = (const float*)d_in[3];
    const float* W1  = (const float*)d_in[4];  const float* b1 = (const float*)d_in[5];
    const float* W2  = (const float*)d_in[6];  const float* b2 = (const float*)d_in[7];
    const float* W3  = (const float*)d_in[8];  const float* b3 = (const float*)d_in[9];
    const float* W4  = (const float*)d_in[10]; const float* b4 = (const float*)d_in[11];
    const float* W5  = (const float*)d_in[12]; const float* b5 = (const float*)d_in[13];
    float* out = (float*)d_out;

    const int N = in_sizes[0] / NFEAT;
    const int E = in_sizes[1];
    const int NB = (N + 255) >> 8;   // 256-node buckets

    // ws layout, every region 256B-aligned
    char* w = (char*)d_ws;
    auto alloc = [&](size_t bytes) {
        char* p = w; w += (bytes + 255) & ~(size_t)255; return p;
    };
    int* off2     = (int*)alloc((size_t)N * 2 * 4);
    int* gCur     = (int*)alloc((size_t)NB * 4);
    u64* gStage   = (u64*)alloc((size_t)NB * CAP * 8);
    unsigned* pe  = (unsigned*)alloc((size_t)NB * CAP * 4);
    ushort_t* B   = (ushort_t*)alloc((size_t)N * 64 * 2);
    ushort_t* D   = (ushort_t*)alloc((size_t)N * 64 * 2);
    ushort_t* AG  = (ushort_t*)alloc((size_t)N * 64 * 2);
    float* nrm    = (float*)alloc((size_t)N * 4);
    float* hbs    = (float*)alloc(192 * 4);
    float* hbns   = (float*)alloc(4 * 4);
    ushort_t* Bpk1 = (ushort_t*)alloc(8192 * 2);
    ushort_t* Bpk2 = (ushort_t*)alloc(4096 * 2);
    ushort_t* Bpk3 = (ushort_t*)alloc(4096 * 2);
    ushort_t* Bpk4 = (ushort_t*)alloc(2048 * 2);
    ushort_t* Bpk5 = (ushort_t*)alloc(512 * 2);

    dim3 blk(256);
    int actBlocks  = (N + 15) / 16;
    int gemmBlocks = (N + 63) / 64;
    int sortBlocks = (E + CHUNK - 1) / CHUNK;
    int tiles      = (N + 63) / 64;
    int aggqBlocks = 8 * ((tiles + 1) / 2);

    // prep: weight packs + biases + cursor zeroing
    k_prep<<<76, blk, 0, stream>>>(W1, W2, W3, W4, W5, b1, b2, b3,
                                   Bpk1, Bpk2, Bpk3, Bpk4, Bpk5, hbs, hbns,
                                   gCur, NB);

    // fused: edge bucket-scatter || layer-1 GEMM (independent)
    k_gemm1_scatter<<<sortBlocks + gemmBlocks, blk, 0, stream>>>(
        x, Bpk1, hbs, hbns, B, N, sortBlocks, dst, src, adj, gCur, gStage, E, NB);

    // per-bucket finalize: (beg,end) pairs + node-sorted pe
    k_bfinal<<<NB, blk, 0, stream>>>(gStage, gCur, off2, pe, N);

    // layer 1: quartered agg -> act
    k_aggq<<<aggqBlocks, blk, 0, stream>>>(B, off2, pe, AG, N);
    k_act<false><<<actBlocks, blk, 0, stream>>>(AG, D, nrm, N);
    // layer 2
    k_gemm64<<<gemmBlocks, blk, 0, stream>>>(D, nrm, Bpk2, hbs + 64, hbns + 1, B, N);
    k_aggq<<<aggqBlocks, blk, 0, stream>>>(B, off2, pe, AG, N);
    k_act<false><<<actBlocks, blk, 0, stream>>>(AG, D, nrm, N);
    // layer 3
    k_gemm64<<<gemmBlocks, blk, 0, stream>>>(D, nrm, Bpk3, hbs + 128, hbns + 2, B, N);
    k_aggq<<<aggqBlocks, blk, 0, stream>>>(B, off2, pe, AG, N);
    k_act<true><<<actBlocks, blk, 0, stream>>>(AG, D, nullptr, N);

    // head (MFMA)
    k_head<<<gemmBlocks, blk, 0, stream>>>(D, Bpk4, b4, Bpk5, b5, out, N);
}

// Round 18
// 205.923 us; speedup vs baseline: 1.9801x; 1.9801x over previous
//
#include <hip/hip_runtime.h>
#include <hip/hip_fp16.h>
#include <math.h>

#define NFEAT 128
#define NHID  64
#define ATH996 3.106303f   // artanh(0.996)
#define CHUNK 4096         // edges per sort block
#define CAP   6144         // fixed capacity per 256-node bucket (mean ~4092)

typedef __attribute__((ext_vector_type(8))) _Float16 half8;
typedef __attribute__((ext_vector_type(4))) float floatx4;
typedef unsigned short ushort_t;
typedef unsigned long long u64;

__device__ __forceinline__ float wave_sum(float v) {
#pragma unroll
    for (int m = 1; m < 64; m <<= 1) v += __shfl_xor(v, m, 64);
    return v;
}

__device__ __forceinline__ float fast_tanh(float x) {
    float e = __expf(2.f * x);
    return 1.f - 2.f / (e + 1.f);
}

__device__ __forceinline__ float artanh_clip(float v) {
    const float lim = 0.99999988f;  // float(1 - 1e-7)
    v = fminf(fmaxf(v, -lim), lim);
    return 0.5f * __logf((1.f + v) / (1.f - v));
}

__device__ __forceinline__ ushort_t f2h(float f) {
    __half h = __float2half(f);
    return *(ushort_t*)&h;
}

__device__ __forceinline__ unsigned pk2h(float a, float b) {
    return (unsigned)f2h(a) | ((unsigned)f2h(b) << 16);
}

// packed edge: bits[31:15] = src (17b), bits[14:0] = fp16(adj) sans sign
__device__ __forceinline__ __half pe_adjh(unsigned p) {
    return __ushort_as_half((ushort_t)(p & 0x7fffu));
}

// ---- one-shot prep: weight packs (fp16) + biases + cursor zeroing -----------
__global__ __launch_bounds__(256) void k_prep(
        const float* __restrict__ W1, const float* __restrict__ W2,
        const float* __restrict__ W3, const float* __restrict__ W4,
        const float* __restrict__ W5, const float* __restrict__ b1,
        const float* __restrict__ b2, const float* __restrict__ b3,
        ushort_t* __restrict__ Bpk1, ushort_t* __restrict__ Bpk2,
        ushort_t* __restrict__ Bpk3, ushort_t* __restrict__ Bpk4,
        ushort_t* __restrict__ Bpk5, float* __restrict__ hbs,
        float* __restrict__ hbns, int* __restrict__ gCur, int nb) {
    int bid = blockIdx.x, tid = threadIdx.x;
    if (bid >= 75) {
        for (int t = tid; t < nb; t += 256) gCur[t] = 0;
        return;
    }
    if (bid < 64) {
        const float* W; ushort_t* Bpk; int K, o;
        if (bid < 32)      { W = W1; Bpk = Bpk1; K = 128; o = bid * 256 + tid; }
        else if (bid < 48) { W = W2; Bpk = Bpk2; K = 64;  o = (bid - 32) * 256 + tid; }
        else               { W = W3; Bpk = Bpk3; K = 64;  o = (bid - 48) * 256 + tid; }
        int j = o & 7, c = (o >> 3) & 15, nf = (o >> 7) & 3, hi = (o >> 9) & 3,
            ks = o >> 11;
        Bpk[o] = f2h(W[(nf * 16 + c) * K + ks * 32 + hi * 8 + j]);
    } else if (bid < 72) {
        int o = (bid - 64) * 256 + tid;
        int j = o & 7, c = (o >> 3) & 15, nf = (o >> 7) & 1, hi = (o >> 8) & 3,
            ks = o >> 10;
        Bpk4[o] = f2h(W4[(nf * 16 + c) * 64 + ks * 32 + hi * 8 + j]);
    } else if (bid < 74) {
        int o = (bid - 72) * 256 + tid;
        if (o < 512) {
            int j = o & 7, c = (o >> 3) & 15, hi = o >> 7;
            Bpk5[o] = f2h(W5[c * 32 + hi * 8 + j]);
        }
    } else {
        if (tid < 192) {
            int wv = tid >> 6, lane = tid & 63;
            const float* b = (wv == 0) ? b1 : (wv == 1) ? b2 : b3;
            float bv = b[lane];
            float bn = fmaxf(sqrtf(wave_sum(bv * bv)), 1e-15f);
            float th = fast_tanh(bn);
            float f = th / bn;
            float hn = th;
            if (th > 0.996f) { f = 0.996f / bn; hn = 0.996f; }
            hbs[wv * 64 + lane] = bv * f;
            if (lane == 0) hbns[wv] = hn;
        }
    }
}

// epilogue transform on one row's 4 nf-values (16-lane-group reductions)
__device__ __forceinline__ void epi_vals(const float vin[4], float pn,
        float hbn, const float* __restrict__ hb, int c, float outv[4]) {
    float pp = 0.f;
#pragma unroll
    for (int nf = 0; nf < 4; ++nf) pp += vin[nf] * vin[nf];
#pragma unroll
    for (int m = 1; m < 16; m <<= 1) pp += __shfl_xor(pp, m, 64);
    float mpn = sqrtf(pp);
    float an = artanh_clip(pn);
    if (hbn <= 1e-15f) {
        float targ = (mpn / pn) * an;
        float scale = (targ > ATH996) ? (ATH996 / mpn) : (an / pn);
        if (mpn <= 1e-15f) scale = 0.f;
#pragma unroll
        for (int nf = 0; nf < 4; ++nf) outv[nf] = vin[nf] * scale;
    } else {
        float targ = (mpn / pn) * an;
        float th = fast_tanh(targ);
        float rn = fminf(th, 0.996f);
        float rs = (mpn <= 1e-15f) ? 0.f : (rn / mpn);
        float res[4], xyp = 0.f;
#pragma unroll
        for (int nf = 0; nf < 4; ++nf) {
            res[nf] = vin[nf] * rs;
            xyp += res[nf] * hb[nf * 16 + c];
        }
#pragma unroll
        for (int m = 1; m < 16; m <<= 1) xyp += __shfl_xor(xyp, m, 64);
        float x2 = rn * rn, y2 = hbn * hbn;
        float den = fmaxf(1.f + 2.f * xyp + x2 * y2, 1e-15f);
        float ca = (1.f + 2.f * xyp + y2) / den, cb = (1.f - x2) / den;
        float mv[4], mm = 0.f;
#pragma unroll
        for (int nf = 0; nf < 4; ++nf) {
            mv[nf] = ca * res[nf] + cb * hb[nf * 16 + c];
            mm += mv[nf] * mv[nf];
        }
#pragma unroll
        for (int m = 1; m < 16; m <<= 1) mm += __shfl_xor(mm, m, 64);
        float mn = sqrtf(mm);
        float mc = fminf(fmaxf(mn, 1e-15f), 0.996f);
        float msc = ((mn > 0.996f) ? (0.996f / mn) : 1.f) * artanh_clip(mc) / mc;
#pragma unroll
        for (int nf = 0; nf < 4; ++nf) outv[nf] = mv[nf] * msc;
    }
}

// fused: blocks [0,sortBlocks) = edge bucket-scatter (fixed-capacity regions);
// blocks [sortBlocks, ...) = layer-1 GEMM. Independent -> true overlap.
__global__ __launch_bounds__(256) void k_gemm1_scatter(
        const float* __restrict__ x, const ushort_t* __restrict__ Bpk,
        const float* __restrict__ hb, const float* __restrict__ hbn_p,
        ushort_t* __restrict__ htout, int n, int sortBlocks,
        const int* __restrict__ dst, const int* __restrict__ src,
        const float* __restrict__ adj, int* __restrict__ gCur,
        u64* __restrict__ gStage, int e, int nb) {
    __shared__ __align__(16) unsigned char smem[41984];
    int tid = threadIdx.x;
    if ((int)blockIdx.x < sortBlocks) {
        u64* stage   = (u64*)smem;                     // CHUNK*8 = 32768
        int* cnt     = (int*)(smem + 32768);           // 512*4
        int* excl    = cnt + 512;
        int* rcnt    = excl + 512;
        int* myBase  = rcnt + 512;
        int* s       = myBase + 512;                   // 256*4
        int start = blockIdx.x * CHUNK, end = min(e, start + CHUNK);
        for (int t = tid; t < nb; t += 256) { cnt[t] = 0; rcnt[t] = 0; }
        __syncthreads();
        for (int i = start + tid; i < end; i += 256)
            atomicAdd(&cnt[dst[i] >> 8], 1);
        __syncthreads();
        int v0 = (2 * tid < nb) ? cnt[2 * tid] : 0;
        int v1 = (2 * tid + 1 < nb) ? cnt[2 * tid + 1] : 0;
        int tsum = v0 + v1;
        s[tid] = tsum; __syncthreads();
        for (int o = 1; o < 256; o <<= 1) {
            int v = (tid >= o) ? s[tid - o] : 0;
            __syncthreads();
            s[tid] += v;
            __syncthreads();
        }
        int ex = s[tid] - tsum;
        if (2 * tid < nb) excl[2 * tid] = ex;
        if (2 * tid + 1 < nb) excl[2 * tid + 1] = ex + v0;
        __syncthreads();
        for (int t = tid; t < nb; t += 256)
            if (cnt[t]) myBase[t] = t * CAP + atomicAdd(&gCur[t], cnt[t]);
        for (int i = start + tid; i < end; i += 256) {
            int d = dst[i];
            int b = d >> 8;
            unsigned ab = (unsigned)__half_as_ushort(__float2half(adj[i])) & 0x7fffu;
            u64 u = ((u64)(unsigned)d << 32) |
                    (u64)(((unsigned)src[i] << 15) | ab);
            int r = atomicAdd(&rcnt[b], 1);
            stage[excl[b] + r] = u;
        }
        __syncthreads();
        int sz = end - start;
        for (int j = tid; j < sz; j += 256) {
            u64 u = stage[j];
            int b = (int)(u >> 40) & 0x1ff;   // dst>>8
            gStage[myBase[b] + (j - excl[b])] = u;
        }
        return;
    }
    // ---- layer-1 GEMM (scale folded into epilogue), fp16 ----
    constexpr int RB = 256;
    unsigned char* As = smem;                           // 64*256 = 16384
    float* pns = (float*)(smem + 16384);                // 64
    float* fs  = pns + 64;                              // 64
    int wv = tid >> 6, lane = tid & 63;
    int grp = lane >> 4, l = lane & 15;
    int rowBase = ((int)blockIdx.x - sortBlocks) * 64;
#pragma unroll
    for (int it = 0; it < 4; ++it) {
        int row = wv * 16 + it * 4 + grp, rg = rowBase + row;
        float4 va = make_float4(0.f, 0.f, 0.f, 0.f), vb = va;
        if (rg < n) {
            const float4* xr = (const float4*)(x + (size_t)rg * NFEAT + l * 8);
            va = xr[0]; vb = xr[1];
        }
        uint4 pk;
        pk.x = pk2h(va.x, va.y); pk.y = pk2h(va.z, va.w);
        pk.z = pk2h(vb.x, vb.y); pk.w = pk2h(vb.z, vb.w);
        unsigned byte = (unsigned)(row * RB + l * 16) ^ ((row & 7) << 4);
        *(uint4*)(As + byte) = pk;
        float ss = va.x * va.x + va.y * va.y + va.z * va.z + va.w * va.w +
                   vb.x * vb.x + vb.y * vb.y + vb.z * vb.z + vb.w * vb.w;
#pragma unroll
        for (int m = 1; m < 16; m <<= 1) ss += __shfl_xor(ss, m, 64);
        if (l == 0) {
            float nr = fmaxf(sqrtf(ss), 1e-15f);
            float th = fast_tanh(nr);
            float f = th / nr;
            float pn = fmaxf(th, 1e-15f);
            if (th > 0.996f) { f = 0.996f / nr; pn = 0.996f; }
            pns[row] = pn; fs[row] = f;
        }
    }
    int hi = lane >> 4, c = lane & 15;
    half8 bf[4][4];
#pragma unroll
    for (int ks = 0; ks < 4; ++ks)
#pragma unroll
        for (int nf = 0; nf < 4; ++nf)
            bf[ks][nf] = *(const half8*)(Bpk + (((size_t)(ks * 4 + hi) * 4 + nf) * 16 + c) * 8);
    floatx4 acc[4];
#pragma unroll
    for (int nf = 0; nf < 4; ++nf)
#pragma unroll
        for (int r = 0; r < 4; ++r) acc[nf][r] = 0.f;
    int arow = wv * 16 + c;
#pragma unroll
    for (int ks = 0; ks < 4; ++ks) {
        unsigned byte = (unsigned)(arow * RB + ks * 64 + hi * 16) ^ ((arow & 7) << 4);
        half8 af = *(const half8*)(As + byte);
#pragma unroll
        for (int nf = 0; nf < 4; ++nf)
            acc[nf] = __builtin_amdgcn_mfma_f32_16x16x32_f16(af, bf[ks][nf], acc[nf], 0, 0, 0);
    }
    float hbn = hbn_p[0];
#pragma unroll
    for (int r = 0; r < 4; ++r) {
        int row = wv * 16 + hi * 4 + r, rg = rowBase + row;
        float f = fs[row];
        float vin[4], outv[4];
#pragma unroll
        for (int nf = 0; nf < 4; ++nf) vin[nf] = acc[nf][r] * f;
        epi_vals(vin, pns[row], hbn, hb, c, outv);
        if (rg < n) {
#pragma unroll
            for (int nf = 0; nf < 4; ++nf)
                htout[(size_t)rg * 64 + nf * 16 + c] = f2h(outv[nf]);
        }
    }
}

// per-bucket finalize: local node histogram -> (beg,end) pairs; rank-scatter pe
__global__ __launch_bounds__(256) void k_bfinal(const u64* __restrict__ gStage,
        const int* __restrict__ gCur, int* __restrict__ off2,
        unsigned* __restrict__ pe, int n) {
    __shared__ int ncnt[256], nexcl[256], rcnt[256], s[256];
    int tid = threadIdx.x, b = blockIdx.x;
    int base = b * CAP;
    int ecnt = gCur[b];
    int nbeg = b << 8;
    ncnt[tid] = 0; rcnt[tid] = 0;
    __syncthreads();
    for (int j = tid; j < ecnt; j += 256) {
        int dl = ((int)(gStage[base + j] >> 32) & 0x1ffff) - nbeg;
        atomicAdd(&ncnt[dl], 1);
    }
    __syncthreads();
    int v = ncnt[tid];
    s[tid] = v; __syncthreads();
    for (int o = 1; o < 256; o <<= 1) {
        int t2 = (tid >= o) ? s[tid - o] : 0;
        __syncthreads();
        s[tid] += t2;
        __syncthreads();
    }
    nexcl[tid] = s[tid] - v;
    int node = nbeg + tid;
    if (node < n) {
        off2[2 * node]     = base + nexcl[tid];
        off2[2 * node + 1] = base + nexcl[tid] + v;
    }
    __syncthreads();
    for (int j = tid; j < ecnt; j += 256) {
        u64 u = gStage[base + j];
        int dl = ((int)(u >> 32) & 0x1ffff) - nbeg;
        int r = atomicAdd(&rcnt[dl], 1);
        pe[base + nexcl[dl] + r] = (unsigned)u;
    }
}

// layers 2/3 GEMM (8B/lane staging), fp16
__global__ __launch_bounds__(256) void k_gemm64(
        const ushort_t* __restrict__ h, const float* __restrict__ nrm_in,
        const ushort_t* __restrict__ Bpk, const float* __restrict__ hb,
        const float* __restrict__ hbn_p, ushort_t* __restrict__ htout, int n) {
    constexpr int RB = 128;
    __shared__ __align__(16) unsigned char As[64 * RB];
    int tid = threadIdx.x, wv = tid >> 6, lane = tid & 63;
    int grp = lane >> 4, l = lane & 15;
    int rowBase = blockIdx.x * 64;
#pragma unroll
    for (int it = 0; it < 4; ++it) {
        int row = wv * 16 + it * 4 + grp, rg = rowBase + row;
        uint2 pk = make_uint2(0u, 0u);
        if (rg < n) pk = *(const uint2*)(h + (size_t)rg * 64 + l * 4);
        unsigned byte = (unsigned)(row * RB + l * 8) ^ ((row & 7) << 4);
        *(uint2*)(As + byte) = pk;
    }
    int hi = lane >> 4, c = lane & 15;
    half8 bf[2][4];
#pragma unroll
    for (int ks = 0; ks < 2; ++ks)
#pragma unroll
        for (int nf = 0; nf < 4; ++nf)
            bf[ks][nf] = *(const half8*)(Bpk + (((size_t)(ks * 4 + hi) * 4 + nf) * 16 + c) * 8);
    floatx4 acc[4];
#pragma unroll
    for (int nf = 0; nf < 4; ++nf)
#pragma unroll
        for (int r = 0; r < 4; ++r) acc[nf][r] = 0.f;
    int arow = wv * 16 + c;
#pragma unroll
    for (int ks = 0; ks < 2; ++ks) {
        unsigned byte = (unsigned)(arow * RB + ks * 64 + hi * 16) ^ ((arow & 7) << 4);
        half8 af = *(const half8*)(As + byte);
#pragma unroll
        for (int nf = 0; nf < 4; ++nf)
            acc[nf] = __builtin_amdgcn_mfma_f32_16x16x32_f16(af, bf[ks][nf], acc[nf], 0, 0, 0);
    }
    float hbn = hbn_p[0];
#pragma unroll
    for (int r = 0; r < 4; ++r) {
        int row = wv * 16 + hi * 4 + r, rg = rowBase + row;
        float pn = (rg < n) ? nrm_in[rg] : 1e-15f;
        float vin[4], outv[4];
#pragma unroll
        for (int nf = 0; nf < 4; ++nf) vin[nf] = acc[nf][r];
        epi_vals(vin, pn, hbn, hb, c, outv);
        if (rg < n) {
#pragma unroll
            for (int nf = 0; nf < 4; ++nf)
                htout[(size_t)rg * 64 + nf * 16 + c] = f2h(outv[nf]);
        }
    }
}

// CSR aggregation + HypAct. 16 lanes/node; 8-deep edge ILP; packed fp16 FMA.
template <bool TANGENT_OUT>
__global__ __launch_bounds__(256) void k_agg_act(
        const ushort_t* __restrict__ ht, const int* __restrict__ off2,
        const unsigned* __restrict__ pe, ushort_t* __restrict__ hout,
        float* __restrict__ nrm_out, int n) {
    int tid = threadIdx.x;
    int grp = tid >> 4, l = tid & 15;
    int node = blockIdx.x * 16 + grp;
    if (node >= n) return;
    int beg = off2[2 * node], end = off2[2 * node + 1];
    const char* hb8 = (const char*)ht + l * 8;
    __half2 ax[4], ay[4];
#pragma unroll
    for (int u = 0; u < 4; ++u) {
        ax[u] = __float2half2_rn(0.f);
        ay[u] = __float2half2_rn(0.f);
    }
    int e = beg;
    for (; e + 7 < end; e += 8) {
        unsigned p[8];
#pragma unroll
        for (int u = 0; u < 8; ++u) p[u] = pe[e + u];
        uint2 rr[8];
#pragma unroll
        for (int u = 0; u < 8; ++u)
            rr[u] = *(const uint2*)(hb8 + ((size_t)(p[u] >> 15) << 7));
#pragma unroll
        for (int u = 0; u < 8; ++u) {
            __half2 w2 = __half2half2(pe_adjh(p[u]));
            ax[u & 3] = __hfma2(w2, *(__half2*)&rr[u].x, ax[u & 3]);
            ay[u & 3] = __hfma2(w2, *(__half2*)&rr[u].y, ay[u & 3]);
        }
    }
    for (; e < end; ++e) {
        unsigned p = pe[e];
        uint2 r = *(const uint2*)(hb8 + ((size_t)(p >> 15) << 7));
        __half2 w2 = __half2half2(pe_adjh(p));
        ax[0] = __hfma2(w2, *(__half2*)&r.x, ax[0]);
        ay[0] = __hfma2(w2, *(__half2*)&r.y, ay[0]);
    }
    float f0 = 0.f, f1 = 0.f, f2 = 0.f, f3 = 0.f;
#pragma unroll
    for (int u = 0; u < 4; ++u) {
        float2 vx = __half22float2(ax[u]);
        float2 vy = __half22float2(ay[u]);
        f0 += vx.x; f1 += vx.y; f2 += vy.x; f3 += vy.y;
    }
    float ss = f0 * f0 + f1 * f1 + f2 * f2 + f3 * f3;
#pragma unroll
    for (int m = 1; m < 16; m <<= 1) ss += __shfl_xor(ss, m, 64);
    float un = fmaxf(sqrtf(ss), 1e-15f);
    float thu = fast_tanh(un);
    float pf = thu / un, pn = thu;
    if (thu > 0.996f) { pf = 0.996f / un; pn = 0.996f; }
    float pnc = fmaxf(pn, 1e-15f);
    float ls = artanh_clip(pnc) / pnc * pf;   // logmap0(proj(expmap0(.))) scale
    float t0 = fmaxf(ls * f0, 0.f), t1 = fmaxf(ls * f1, 0.f);
    float t2 = fmaxf(ls * f2, 0.f), t3 = fmaxf(ls * f3, 0.f);
    float ss2 = t0 * t0 + t1 * t1 + t2 * t2 + t3 * t3;
#pragma unroll
    for (int m = 1; m < 16; m <<= 1) ss2 += __shfl_xor(ss2, m, 64);
    float tn = fmaxf(sqrtf(ss2), 1e-15f);
    uint2 ov;
    if (TANGENT_OUT) {
        float sc = (tn > ATH996) ? (ATH996 / tn) : 1.f;
        ov = make_uint2(pk2h(t0 * sc, t1 * sc), pk2h(t2 * sc, t3 * sc));
    } else {
        float tht = fast_tanh(tn);
        float rf = tht / tn, rn = tht;
        if (tht > 0.996f) { rf = 0.996f / tn; rn = 0.996f; }
        ov = make_uint2(pk2h(rf * t0, rf * t1), pk2h(rf * t2, rf * t3));
        if (l == 0) nrm_out[node] = fmaxf(rn, 1e-15f);
    }
    *(uint2*)((char*)hout + (size_t)node * 128 + l * 8) = ov;
}

// MFMA head: z = relu(t@W4.T+b4); out = log_softmax(z@W5.T+b5), fp16
__global__ __launch_bounds__(256) void k_head(
        const ushort_t* __restrict__ t_in, const ushort_t* __restrict__ Bpk4,
        const float* __restrict__ b4, const ushort_t* __restrict__ Bpk5,
        const float* __restrict__ b5, float* __restrict__ out, int n) {
    constexpr int RB = 128;
    __shared__ __align__(16) unsigned char As[64 * RB];
    __shared__ __align__(16) unsigned char Zs[4][16 * 80];  // 80B rows: 2-way max
    int tid = threadIdx.x, wv = tid >> 6, lane = tid & 63;
    int grp = lane >> 4, l = lane & 15;
    int rowBase = blockIdx.x * 64;
#pragma unroll
    for (int it = 0; it < 4; ++it) {
        int row = wv * 16 + it * 4 + grp, rg = rowBase + row;
        uint2 pk = make_uint2(0u, 0u);
        if (rg < n) pk = *(const uint2*)(t_in + (size_t)rg * 64 + l * 4);
        unsigned byte = (unsigned)(row * RB + l * 8) ^ ((row & 7) << 4);
        *(uint2*)(As + byte) = pk;
    }
    int hi = lane >> 4, c = lane & 15;
    half8 bf4[2][2];
#pragma unroll
    for (int ks = 0; ks < 2; ++ks)
#pragma unroll
        for (int nf = 0; nf < 2; ++nf)
            bf4[ks][nf] = *(const half8*)(Bpk4 + (((size_t)(ks * 4 + hi) * 2 + nf) * 16 + c) * 8);
    floatx4 acc[2];
#pragma unroll
    for (int nf = 0; nf < 2; ++nf)
#pragma unroll
        for (int r = 0; r < 4; ++r) acc[nf][r] = 0.f;
    int arow = wv * 16 + c;
#pragma unroll
    for (int ks = 0; ks < 2; ++ks) {
        unsigned byte = (unsigned)(arow * RB + ks * 64 + hi * 16) ^ ((arow & 7) << 4);
        half8 af = *(const half8*)(As + byte);
#pragma unroll
        for (int nf = 0; nf < 2; ++nf)
            acc[nf] = __builtin_amdgcn_mfma_f32_16x16x32_f16(af, bf4[ks][nf], acc[nf], 0, 0, 0);
    }
    float bb0 = b4[c], bb1 = b4[16 + c];
#pragma unroll
    for (int r = 0; r < 4; ++r) {
        int zr = hi * 4 + r;
        *(ushort_t*)(Zs[wv] + zr * 80 + c * 2) = f2h(fmaxf(acc[0][r] + bb0, 0.f));
        *(ushort_t*)(Zs[wv] + zr * 80 + (16 + c) * 2) = f2h(fmaxf(acc[1][r] + bb1, 0.f));
    }
    half8 bf5 = *(const half8*)(Bpk5 + ((size_t)(hi * 16 + c)) * 8);
    half8 zf = *(const half8*)(Zs[wv] + c * 80 + hi * 16);
    floatx4 acc5;
#pragma unroll
    for (int r = 0; r < 4; ++r) acc5[r] = 0.f;
    acc5 = __builtin_amdgcn_mfma_f32_16x16x32_f16(zf, bf5, acc5, 0, 0, 0);
    float b5v = b5[c];
#pragma unroll
    for (int r = 0; r < 4; ++r) {
        float y = acc5[r] + b5v;
        float mx = y;
#pragma unroll
        for (int mk = 1; mk < 16; mk <<= 1) mx = fmaxf(mx, __shfl_xor(mx, mk, 64));
        float sm = __expf(y - mx);
#pragma unroll
        for (int mk = 1; mk < 16; mk <<= 1) sm += __shfl_xor(sm, mk, 64);
        int rg = rowBase + wv * 16 + hi * 4 + r;
        if (rg < n) out[(size_t)rg * 16 + c] = y - mx - __logf(sm);
    }
}

extern "C" void kernel_launch(void* const* d_in, const int* in_sizes, int n_in,
                              void* d_out, int out_size, void* d_ws, size_t ws_size,
                              hipStream_t stream) {
    const float* x   = (const float*)d_in[0];
    const int*   src = (const int*)d_in[1];
    const int*   dst = (const int*)d_in[2];
    const float* adj = (const float*)d_in[3];
    const float* W1  = (const float*)d_in[4];  const float* b1 = (const float*)d_in[5];
    const float* W2  = (const float*)d_in[6];  const float* b2 = (const float*)d_in[7];
    const float* W3  = (const float*)d_in[8];  const float* b3 = (const float*)d_in[9];
    const float* W4  = (const float*)d_in[10]; const float* b4 = (const float*)d_in[11];
    const float* W5  = (const float*)d_in[12]; const float* b5 = (const float*)d_in[13];
    float* out = (float*)d_out;

    const int N = in_sizes[0] / NFEAT;
    const int E = in_sizes[1];
    const int NB = (N + 255) >> 8;   // 256-node buckets

    // ws layout, every region 256B-aligned
    char* w = (char*)d_ws;
    auto alloc = [&](size_t bytes) {
        char* p = w; w += (bytes + 255) & ~(size_t)255; return p;
    };
    int* off2     = (int*)alloc((size_t)N * 2 * 4);
    int* gCur     = (int*)alloc((size_t)NB * 4);
    u64* gStage   = (u64*)alloc((size_t)NB * CAP * 8);
    unsigned* pe  = (unsigned*)alloc((size_t)NB * CAP * 4);
    ushort_t* B   = (ushort_t*)alloc((size_t)N * 64 * 2);
    ushort_t* D   = (ushort_t*)alloc((size_t)N * 64 * 2);
    float* nrm    = (float*)alloc((size_t)N * 4);
    float* hbs    = (float*)alloc(192 * 4);
    float* hbns   = (float*)alloc(4 * 4);
    ushort_t* Bpk1 = (ushort_t*)alloc(8192 * 2);
    ushort_t* Bpk2 = (ushort_t*)alloc(4096 * 2);
    ushort_t* Bpk3 = (ushort_t*)alloc(4096 * 2);
    ushort_t* Bpk4 = (ushort_t*)alloc(2048 * 2);
    ushort_t* Bpk5 = (ushort_t*)alloc(512 * 2);

    dim3 blk(256);
    int aggBlocks  = (N + 15) / 16;
    int gemmBlocks = (N + 63) / 64;
    int sortBlocks = (E + CHUNK - 1) / CHUNK;

    // prep: weight packs + biases + cursor zeroing
    k_prep<<<76, blk, 0, stream>>>(W1, W2, W3, W4, W5, b1, b2, b3,
                                   Bpk1, Bpk2, Bpk3, Bpk4, Bpk5, hbs, hbns,
                                   gCur, NB);

    // fused: edge bucket-scatter || layer-1 GEMM (independent)
    k_gemm1_scatter<<<sortBlocks + gemmBlocks, blk, 0, stream>>>(
        x, Bpk1, hbs, hbns, B, N, sortBlocks, dst, src, adj, gCur, gStage, E, NB);

    // per-bucket finalize: (beg,end) pairs + node-sorted pe
    k_bfinal<<<NB, blk, 0, stream>>>(gStage, gCur, off2, pe, N);

    // layer 1 aggregation (+act)
    k_agg_act<false><<<aggBlocks, blk, 0, stream>>>(B, off2, pe, D, nrm, N);
    // layer 2
    k_gemm64<<<gemmBlocks, blk, 0, stream>>>(D, nrm, Bpk2, hbs + 64, hbns + 1, B, N);
    k_agg_act<false><<<aggBlocks, blk, 0, stream>>>(B, off2, pe, D, nrm, N);
    // layer 3
    k_gemm64<<<gemmBlocks, blk, 0, stream>>>(D, nrm, Bpk3, hbs + 128, hbns + 2, B, N);
    k_agg_act<true><<<aggBlocks, blk, 0, stream>>>(B, off2, pe, D, nullptr, N);

    // head (MFMA)
    k_head<<<gemmBlocks, blk, 0, stream>>>(D, Bpk4, b4, Bpk5, b5, out, N);
}